// Round 1
// baseline (349.513 us; speedup 1.0000x reference)
//
#include <hip/hip_runtime.h>
#include <math.h>

// Problem dims (fixed by setup_inputs)
constexpr int B  = 16;
constexpr int H  = 32;
constexpr int S  = 2048;
constexpr int DK = 128;
constexpr int D  = 4096;   // H*DK
constexpr int BH = B * H;  // 512

constexpr int NSPLIT = 4;          // S-splits per (b,h)
constexpr int CHUNK  = S / NSPLIT; // 512
constexpr int NREC   = NSPLIT * 4; // 4 waves per block -> 16 partial records per bh
constexpr int REC    = 132;        // floats per record: acc[128], m, l, pad2

// ---------------------------------------------------------------------------
// Projection GEMV: Y[b][n] = sum_d X[b][d] * W[n][d]
// One wave handles 4 consecutive columns n for all 16 batches.
// Block = 256 threads (4 waves) -> 16 columns per block.
// Three weights / three outputs so QKV is a single launch; for Wo pass the
// same pointer three times.
// ---------------------------------------------------------------------------
__global__ __launch_bounds__(256) void proj_kernel(
    const float* __restrict__ X,
    const float* __restrict__ W0,
    const float* __restrict__ W1,
    const float* __restrict__ W2,
    float* __restrict__ Y0,
    float* __restrict__ Y1,
    float* __restrict__ Y2)
{
    const int lane = threadIdx.x & 63;
    const int wid  = threadIdx.x >> 6;
    const int c0   = (blockIdx.x * 4 + wid) * 4;   // global column base (4 cols)
    const int wsel = c0 >> 12;                     // which weight
    const int n0   = c0 & (D - 1);

    const float* Wp = (wsel == 0) ? W0 : (wsel == 1) ? W1 : W2;
    float*       Yp = (wsel == 0) ? Y0 : (wsel == 1) ? Y1 : Y2;

    const float4* w0 = (const float4*)(Wp + (size_t)(n0 + 0) * D);
    const float4* w1 = (const float4*)(Wp + (size_t)(n0 + 1) * D);
    const float4* w2 = (const float4*)(Wp + (size_t)(n0 + 2) * D);
    const float4* w3 = (const float4*)(Wp + (size_t)(n0 + 3) * D);
    const float4* x4 = (const float4*)X;           // [16][1024]

    float acc[16][4];
    #pragma unroll
    for (int b = 0; b < 16; ++b) {
        acc[b][0] = 0.f; acc[b][1] = 0.f; acc[b][2] = 0.f; acc[b][3] = 0.f;
    }

    for (int chunk = 0; chunk < 16; ++chunk) {
        const int d4 = chunk * 64 + lane;          // float4 index into a row
        const float4 wv0 = w0[d4];
        const float4 wv1 = w1[d4];
        const float4 wv2 = w2[d4];
        const float4 wv3 = w3[d4];
        #pragma unroll
        for (int b = 0; b < 16; ++b) {
            const float4 xv = x4[b * (D / 4) + d4];
            acc[b][0] += xv.x * wv0.x + xv.y * wv0.y + xv.z * wv0.z + xv.w * wv0.w;
            acc[b][1] += xv.x * wv1.x + xv.y * wv1.y + xv.z * wv1.z + xv.w * wv1.w;
            acc[b][2] += xv.x * wv2.x + xv.y * wv2.y + xv.z * wv2.z + xv.w * wv2.w;
            acc[b][3] += xv.x * wv3.x + xv.y * wv3.y + xv.z * wv3.z + xv.w * wv3.w;
        }
    }

    // Butterfly-reduce each of the 64 accumulators across the wave.
    #pragma unroll
    for (int b = 0; b < 16; ++b) {
        #pragma unroll
        for (int i = 0; i < 4; ++i) {
            float v = acc[b][i];
            #pragma unroll
            for (int off = 32; off; off >>= 1) v += __shfl_xor(v, off, 64);
            acc[b][i] = v;
        }
    }

    // Lane l writes output (b = l>>2, col = l&3). After the butterfly every
    // lane holds all 64 totals; select statically to avoid dynamic reg index.
    float outv = 0.f;
    #pragma unroll
    for (int b = 0; b < 16; ++b) {
        #pragma unroll
        for (int i = 0; i < 4; ++i) {
            if ((lane >> 2) == b && (lane & 3) == i) outv = acc[b][i];
        }
    }
    const int ob = lane >> 2;
    const int oi = lane & 3;
    Yp[(size_t)ob * D + n0 + oi] = outv;
}

// ---------------------------------------------------------------------------
// Flash-decode attention partials. Grid = BH * NSPLIT blocks, 256 threads.
// Each wave processes every 4th position of its split with an independent
// online softmax; partial (acc[128], m, l) written per (bh, split, wave).
// Position s == start_pos reads k_new/v_new (cache is NOT mutated).
// ---------------------------------------------------------------------------
__global__ __launch_bounds__(256) void attn_kernel(
    const float* __restrict__ q,        // [BH][DK]
    const float* __restrict__ k_cache,  // [B][H][S][DK]
    const float* __restrict__ v_cache,
    const float* __restrict__ k_new,    // [BH][DK]
    const float* __restrict__ v_new,
    const int*   __restrict__ start_pos_p,
    float* __restrict__ part)           // [BH][NREC][REC]
{
    const int lane  = threadIdx.x & 63;
    const int wid   = threadIdx.x >> 6;
    const int bh    = blockIdx.x & (BH - 1);
    const int split = blockIdx.x >> 9;

    const int sp      = start_pos_p[0];
    const int end_pos = sp + 1;

    const int s0    = split * CHUNK;
    int s_end = s0 + CHUNK;
    if (s_end > end_pos) s_end = end_pos;

    const float scale = 0.08838834764831845f;  // 1/sqrt(128)
    float2 qv = *(const float2*)(q + (size_t)bh * DK + 2 * lane);
    qv.x *= scale; qv.y *= scale;

    const float* kbase = k_cache + (size_t)bh * S * DK;
    const float* vbase = v_cache + (size_t)bh * S * DK;
    const float* knew  = k_new + (size_t)bh * DK;
    const float* vnew  = v_new + (size_t)bh * DK;

    float m = -INFINITY, l = 0.f, a0 = 0.f, a1 = 0.f;

    for (int s = s0 + wid; s < s_end; s += 4) {
        const bool is_new = (s == sp);
        const float* kp = is_new ? knew : (kbase + (size_t)s * DK);
        const float* vp = is_new ? vnew : (vbase + (size_t)s * DK);
        const float2 kv = *(const float2*)(kp + 2 * lane);
        const float2 vv = *(const float2*)(vp + 2 * lane);

        float p = kv.x * qv.x + kv.y * qv.y;
        #pragma unroll
        for (int off = 32; off; off >>= 1) p += __shfl_xor(p, off, 64);

        const float mn = fmaxf(m, p);
        const float eo = __expf(m - mn);   // first iter: exp(-inf)=0
        const float ep = __expf(p - mn);
        l  = l  * eo + ep;
        a0 = a0 * eo + ep * vv.x;
        a1 = a1 * eo + ep * vv.y;
        m  = mn;
    }

    float* rec = part + ((size_t)bh * NREC + split * 4 + wid) * REC;
    *(float2*)(rec + 2 * lane) = make_float2(a0, a1);
    if (lane == 0) { rec[128] = m; rec[129] = l; }
}

// ---------------------------------------------------------------------------
// Combine NREC partials per (b,h). Grid = BH blocks of 64 threads.
// ---------------------------------------------------------------------------
__global__ __launch_bounds__(64) void combine_kernel(
    const float* __restrict__ part,
    float* __restrict__ attn_out)       // [B][D] laid out as [bh][DK]
{
    const int bh   = blockIdx.x;
    const int lane = threadIdx.x;
    const float* base = part + (size_t)bh * NREC * REC;

    float M = -INFINITY;
    #pragma unroll
    for (int i = 0; i < NREC; ++i) M = fmaxf(M, base[i * REC + 128]);

    float L = 0.f, o0 = 0.f, o1 = 0.f;
    #pragma unroll
    for (int i = 0; i < NREC; ++i) {
        const float mi = base[i * REC + 128];
        const float li = base[i * REC + 129];
        const float w  = __expf(mi - M);
        L += li * w;
        const float2 a = *(const float2*)(base + i * REC + 2 * lane);
        o0 += w * a.x;
        o1 += w * a.y;
    }
    const float inv = 1.f / L;
    attn_out[(size_t)bh * DK + 2 * lane]     = o0 * inv;
    attn_out[(size_t)bh * DK + 2 * lane + 1] = o1 * inv;
}

// ---------------------------------------------------------------------------
extern "C" void kernel_launch(void* const* d_in, const int* in_sizes, int n_in,
                              void* d_out, int out_size, void* d_ws, size_t ws_size,
                              hipStream_t stream)
{
    const float* x       = (const float*)d_in[0];
    const float* k_cache = (const float*)d_in[1];
    const float* v_cache = (const float*)d_in[2];
    const float* Wq      = (const float*)d_in[3];
    const float* Wk      = (const float*)d_in[4];
    const float* Wv      = (const float*)d_in[5];
    const float* Wo      = (const float*)d_in[6];
    const int*   sp      = (const int*)d_in[7];
    float*       out     = (float*)d_out;

    float* ws       = (float*)d_ws;
    float* q        = ws;                    // B*D = 65536 floats
    float* k_new    = ws + 65536;
    float* v_new    = ws + 131072;
    float* attn_out = ws + 196608;
    float* part     = ws + 262144;           // BH*NREC*REC = 1,081,344 floats

    // QKV projections: 3*4096 columns, 16 per block
    proj_kernel<<<(3 * D) / 16, 256, 0, stream>>>(x, Wq, Wk, Wv, q, k_new, v_new);

    // Flash-decode attention partials
    attn_kernel<<<BH * NSPLIT, 256, 0, stream>>>(q, k_cache, v_cache, k_new, v_new,
                                                 sp, part);

    // Merge partials
    combine_kernel<<<BH, 64, 0, stream>>>(part, attn_out);

    // Output projection
    proj_kernel<<<D / 16, 256, 0, stream>>>(attn_out, Wo, Wo, Wo, out, out, out);
}

// Round 2
// 306.868 us; speedup vs baseline: 1.1390x; 1.1390x over previous
//
#include <hip/hip_runtime.h>
#include <math.h>

// Problem dims (fixed by setup_inputs)
constexpr int B  = 16;
constexpr int H  = 32;
constexpr int S  = 2048;
constexpr int DK = 128;
constexpr int D  = 4096;   // H*DK
constexpr int BH = B * H;  // 512

constexpr int NSPLIT = 4;          // S-splits per (b,h)
constexpr int CHUNK  = S / NSPLIT; // 512
constexpr int NREC   = NSPLIT * 4; // 4 waves per block -> 16 partial records per bh
constexpr int REC    = 132;        // floats per record: acc[128], m, l, pad2

// ---------------------------------------------------------------------------
// Merging butterfly: reduce 64 per-lane accumulators across the wave so that
// lane L ends up holding the full-wave total of v[L]. 63 shfl+add pairs.
// ---------------------------------------------------------------------------
__device__ __forceinline__ float reduce64(float v[64], int lane) {
    #pragma unroll
    for (int s = 0; s < 6; ++s) {
        const int off = 1 << s;
        #pragma unroll
        for (int j = 0; j < (64 >> (s + 1)); ++j) {
            const float lo = v[2 * j], hi = v[2 * j + 1];
            const bool  up = (lane & off) != 0;
            const float mine = up ? hi : lo;
            const float oth  = up ? lo : hi;
            v[j] = mine + __shfl_xor(oth, off, 64);
        }
    }
    return v[0];
}

// ---------------------------------------------------------------------------
// QKV projection. Block = 256 threads (4 waves), 16 columns per block
// (4 per wave). x is staged chunk-by-chunk into double-buffered LDS (read
// ONCE per block, shared by all 4 waves); W and x are prefetched one chunk
// ahead so HBM latency hides under the FMA stream. Grid = 3*D/16 = 768.
// ---------------------------------------------------------------------------
__global__ __launch_bounds__(256, 3) void proj_qkv_kernel(
    const float* __restrict__ X,
    const float* __restrict__ W0,
    const float* __restrict__ W1,
    const float* __restrict__ W2,
    float* __restrict__ Y0,
    float* __restrict__ Y1,
    float* __restrict__ Y2)
{
    __shared__ float4 xs[2][16][64];   // [buf][batch][k-float4] = 2 x 16 KB

    const int t    = threadIdx.x;
    const int lane = t & 63;
    const int wid  = t >> 6;
    const int tb   = t >> 4;           // staging: batch 0..15
    const int tf   = t & 15;           // staging: float4 lane 0..15

    const int c0   = blockIdx.x * 16 + wid * 4;  // global column base (4 cols)
    const int wsel = c0 >> 12;
    const int n0   = c0 & (D - 1);

    const float* Wp = (wsel == 0) ? W0 : (wsel == 1) ? W1 : W2;
    float*       Yp = (wsel == 0) ? Y0 : (wsel == 1) ? Y1 : Y2;
    const float4* w4 = (const float4*)Wp;
    const float4* x4 = (const float4*)X;          // [16][1024]

    float acc[64];
    #pragma unroll
    for (int i = 0; i < 64; ++i) acc[i] = 0.f;

    // Prologue: stage chunk 0, prefetch W chunk 0
    float4 xr[4];
    #pragma unroll
    for (int i = 0; i < 4; ++i) xr[i] = x4[tb * 1024 + tf + 16 * i];
    float4 wv[4];
    #pragma unroll
    for (int c = 0; c < 4; ++c) wv[c] = w4[(size_t)(n0 + c) * 1024 + lane];
    #pragma unroll
    for (int i = 0; i < 4; ++i) xs[0][tb][tf + 16 * i] = xr[i];
    __syncthreads();

    for (int ch = 0; ch < 16; ++ch) {
        float4 xn[4], wn[4];
        const bool more = (ch < 15);
        if (more) {
            #pragma unroll
            for (int i = 0; i < 4; ++i)
                xn[i] = x4[tb * 1024 + (ch + 1) * 64 + tf + 16 * i];
            #pragma unroll
            for (int c = 0; c < 4; ++c)
                wn[c] = w4[(size_t)(n0 + c) * 1024 + (ch + 1) * 64 + lane];
        }
        const int buf = ch & 1;
        #pragma unroll
        for (int b = 0; b < 16; ++b) {
            const float4 xv = xs[buf][b][lane];
            #pragma unroll
            for (int c = 0; c < 4; ++c)
                acc[b * 4 + c] += xv.x * wv[c].x + xv.y * wv[c].y +
                                  xv.z * wv[c].z + xv.w * wv[c].w;
        }
        if (more) {
            #pragma unroll
            for (int i = 0; i < 4; ++i) xs[buf ^ 1][tb][tf + 16 * i] = xn[i];
            __syncthreads();
            #pragma unroll
            for (int c = 0; c < 4; ++c) wv[c] = wn[c];
        }
    }

    const float outv = reduce64(acc, lane);
    Yp[(size_t)(lane >> 2) * D + n0 + (lane & 3)] = outv;
}

// ---------------------------------------------------------------------------
// Wo projection. 4 columns per block, K-dim split across the 4 waves
// (1024 elements each), merged via LDS. Grid = D/4 = 1024 blocks.
// x (= attn_out, 256 KB) is L2-hot; W streams from HBM.
// ---------------------------------------------------------------------------
__global__ __launch_bounds__(256) void proj_wo_kernel(
    const float* __restrict__ X,
    const float* __restrict__ Wo,
    float* __restrict__ out)
{
    __shared__ float red[4][64];
    const int lane = threadIdx.x & 63;
    const int wid  = threadIdx.x >> 6;
    const int n0   = blockIdx.x * 4;
    const float4* w4 = (const float4*)Wo;
    const float4* x4 = (const float4*)X;

    float acc[64];
    #pragma unroll
    for (int i = 0; i < 64; ++i) acc[i] = 0.f;

    #pragma unroll
    for (int it = 0; it < 4; ++it) {
        const int d4 = wid * 256 + it * 64 + lane;
        float4 wv[4];
        #pragma unroll
        for (int c = 0; c < 4; ++c) wv[c] = w4[(size_t)(n0 + c) * 1024 + d4];
        #pragma unroll
        for (int b = 0; b < 16; ++b) {
            const float4 xv = x4[b * 1024 + d4];
            #pragma unroll
            for (int c = 0; c < 4; ++c)
                acc[b * 4 + c] += xv.x * wv[c].x + xv.y * wv[c].y +
                                  xv.z * wv[c].z + xv.w * wv[c].w;
        }
    }

    const float pv = reduce64(acc, lane);
    red[wid][lane] = pv;
    __syncthreads();
    if (wid == 0) {
        const float tot = red[0][lane] + red[1][lane] + red[2][lane] + red[3][lane];
        out[(size_t)(lane >> 2) * D + n0 + (lane & 3)] = tot;
    }
}

// ---------------------------------------------------------------------------
// Flash-decode attention partials. Grid = BH * NSPLIT blocks, 256 threads.
// float4 loads: one instruction fetches TWO K (or V) rows (1 KB contiguous);
// each 32-lane half runs an independent online softmax over its position
// stream, halves merged once at the end. Position s == start_pos reads
// k_new/v_new (cache is NOT mutated). Odd tails masked with p = -2e30.
// ---------------------------------------------------------------------------
__global__ __launch_bounds__(256) void attn_kernel(
    const float* __restrict__ q,        // [BH][DK]
    const float* __restrict__ k_cache,  // [B][H][S][DK]
    const float* __restrict__ v_cache,
    const float* __restrict__ k_new,    // [BH][DK]
    const float* __restrict__ v_new,
    const int*   __restrict__ start_pos_p,
    float* __restrict__ part)           // [BH][NREC][REC]
{
    const int lane  = threadIdx.x & 63;
    const int wid   = threadIdx.x >> 6;
    const int half  = lane >> 5;
    const int hl    = lane & 31;
    const int bh    = blockIdx.x & (BH - 1);
    const int split = blockIdx.x >> 9;

    const int sp    = start_pos_p[0];
    const int s0    = split * CHUNK;
    const int lim   = sp + 1;
    const int s_end = (s0 + CHUNK < lim) ? (s0 + CHUNK) : lim;

    const float scale = 0.08838834764831845f;  // 1/sqrt(128)
    float4 qv = *(const float4*)(q + (size_t)bh * DK + 4 * hl);
    qv.x *= scale; qv.y *= scale; qv.z *= scale; qv.w *= scale;

    const float* kbase = k_cache + (size_t)bh * S * DK;
    const float* vbase = v_cache + (size_t)bh * S * DK;
    const float* knew  = k_new + (size_t)bh * DK;
    const float* vnew  = v_new + (size_t)bh * DK;

    float  m = -1e30f, l = 0.f;
    float4 acc = make_float4(0.f, 0.f, 0.f, 0.f);

    for (int s2 = s0 + 2 * wid; s2 < s_end; s2 += 8) {
        const int  pos   = s2 + half;
        const bool valid = pos < s_end;
        const int  cpos  = valid ? pos : (s_end - 1);
        const float* kp = (cpos == sp) ? knew : (kbase + (size_t)cpos * DK);
        const float* vp = (cpos == sp) ? vnew : (vbase + (size_t)cpos * DK);
        const float4 kv = *(const float4*)(kp + 4 * hl);
        const float4 vv = *(const float4*)(vp + 4 * hl);

        float p = kv.x * qv.x + kv.y * qv.y + kv.z * qv.z + kv.w * qv.w;
        p += __shfl_xor(p, 1, 64);
        p += __shfl_xor(p, 2, 64);
        p += __shfl_xor(p, 4, 64);
        p += __shfl_xor(p, 8, 64);
        p += __shfl_xor(p, 16, 64);
        p = valid ? p : -2e30f;

        const float mn = fmaxf(m, p);
        const float eo = __expf(m - mn);
        const float ep = __expf(p - mn);
        l     = l     * eo + ep;
        acc.x = acc.x * eo + ep * vv.x;
        acc.y = acc.y * eo + ep * vv.y;
        acc.z = acc.z * eo + ep * vv.z;
        acc.w = acc.w * eo + ep * vv.w;
        m = mn;
    }

    // Merge the two half-wave softmax states.
    const float m2 = __shfl_xor(m, 32, 64);
    const float M  = fmaxf(m, m2);
    const float w  = __expf(m - M);
    l *= w;
    acc.x *= w; acc.y *= w; acc.z *= w; acc.w *= w;
    l     += __shfl_xor(l, 32, 64);
    acc.x += __shfl_xor(acc.x, 32, 64);
    acc.y += __shfl_xor(acc.y, 32, 64);
    acc.z += __shfl_xor(acc.z, 32, 64);
    acc.w += __shfl_xor(acc.w, 32, 64);

    float* rec = part + ((size_t)bh * NREC + split * 4 + wid) * REC;
    if (half == 0) *(float4*)(rec + 4 * hl) = acc;
    if (lane == 0) { rec[128] = M; rec[129] = l; }
}

// ---------------------------------------------------------------------------
// Combine NREC partials per (b,h). Grid = BH blocks of 64 threads.
// ---------------------------------------------------------------------------
__global__ __launch_bounds__(64) void combine_kernel(
    const float* __restrict__ part,
    float* __restrict__ attn_out)       // [B][D] laid out as [bh][DK]
{
    const int bh   = blockIdx.x;
    const int lane = threadIdx.x;
    const float* base = part + (size_t)bh * NREC * REC;

    float M = -1e30f;
    #pragma unroll
    for (int i = 0; i < NREC; ++i) M = fmaxf(M, base[i * REC + 128]);

    float L = 0.f, o0 = 0.f, o1 = 0.f;
    #pragma unroll
    for (int i = 0; i < NREC; ++i) {
        const float mi = base[i * REC + 128];
        const float li = base[i * REC + 129];
        const float w  = __expf(mi - M);
        L += li * w;
        const float2 a = *(const float2*)(base + i * REC + 2 * lane);
        o0 += w * a.x;
        o1 += w * a.y;
    }
    const float inv = 1.f / L;
    attn_out[(size_t)bh * DK + 2 * lane]     = o0 * inv;
    attn_out[(size_t)bh * DK + 2 * lane + 1] = o1 * inv;
}

// ---------------------------------------------------------------------------
extern "C" void kernel_launch(void* const* d_in, const int* in_sizes, int n_in,
                              void* d_out, int out_size, void* d_ws, size_t ws_size,
                              hipStream_t stream)
{
    const float* x       = (const float*)d_in[0];
    const float* k_cache = (const float*)d_in[1];
    const float* v_cache = (const float*)d_in[2];
    const float* Wq      = (const float*)d_in[3];
    const float* Wk      = (const float*)d_in[4];
    const float* Wv      = (const float*)d_in[5];
    const float* Wo      = (const float*)d_in[6];
    const int*   sp      = (const int*)d_in[7];
    float*       out     = (float*)d_out;

    float* ws       = (float*)d_ws;
    float* q        = ws;                    // B*D = 65536 floats
    float* k_new    = ws + 65536;
    float* v_new    = ws + 131072;
    float* attn_out = ws + 196608;
    float* part     = ws + 262144;           // BH*NREC*REC = 1,081,344 floats

    // QKV projections: 3*4096 columns, 16 per block, x staged in LDS
    proj_qkv_kernel<<<(3 * D) / 16, 256, 0, stream>>>(x, Wq, Wk, Wv, q, k_new, v_new);

    // Flash-decode attention partials
    attn_kernel<<<BH * NSPLIT, 256, 0, stream>>>(q, k_cache, v_cache, k_new, v_new,
                                                 sp, part);

    // Merge partials
    combine_kernel<<<BH, 64, 0, stream>>>(part, attn_out);

    // Output projection: 1024 blocks, K split across waves
    proj_wo_kernel<<<D / 4, 256, 0, stream>>>(attn_out, Wo, out);
}